// Round 7
// baseline (156.369 us; speedup 1.0000x reference)
//
#include <hip/hip_runtime.h>
#include <hip/hip_bf16.h>
#include <math.h>

// Problem constants (from reference): B=2048, I=512, O=512
#define B_DIM 2048
#define I_DIM 512
#define O_DIM 512

constexpr int R_ROWS = 16;               // b-rows per block (ab L2 traffic = 2048/R * 2MB)
constexpr int W_CHUNK = 4;               // i-chunks (threadIdx.y)
constexpr int STAGES = 32;               // 4-i stages per chunk (128 i / 4)

// ws layout: abT [0, 2MB), xt [2MB, 6MB).
//   abT: float4 (a0,b0,a1,b1) at abT[o*256 + p], p = i/2 (0..255) — per-o
//        column is 4KB contiguous -> all hot-loop ab offsets are immediates.
//   xt : float4 xt[g*2048 + q*16 + r] = x[g*16+r][4q..4q+3]; one (g,q) slab
//        = 16 rows x 16B = 256B contiguous.
#define ABT_OFFSET 0
#define XT_OFFSET ((size_t)2 * 1024 * 1024)

// ---------------------------------------------------------------------------
// Setup: blocks [0,512) build abT, blocks [512,1536) re-tile x.
//   factor[b,i,o] = a[i,o] + bcoef[i,o]*x[b,i];  a = 1-w*s, b = w*(2s-1)
// Reads coalesced (lane-fast o / q); writes scattered 16B (small tables).
// ---------------------------------------------------------------------------
__global__ __launch_bounds__(256) void setup_kernel(
    const float* __restrict__ x,
    const float* __restrict__ w_logits,
    const float* __restrict__ s_logits,
    float4* __restrict__ abT,
    float4* __restrict__ xt)
{
    const int blk = blockIdx.x;
    if (blk < 512) {
        int t = blk * 256 + threadIdx.x;          // 0..131071
        int o = t & (O_DIM - 1);                  // lane-fast -> coalesced reads
        int p = t >> 9;                           // i-pair, 0..255
        int i0 = 2 * p;

        float zw0 = w_logits[(i0 + 0) * O_DIM + o];
        float zs0 = s_logits[(i0 + 0) * O_DIM + o];
        float zw1 = w_logits[(i0 + 1) * O_DIM + o];
        float zs1 = s_logits[(i0 + 1) * O_DIM + o];

        float w0 = 1.0f / (1.0f + expf(-zw0));
        float s0 = 1.0f / (1.0f + expf(-zs0));
        float w1 = 1.0f / (1.0f + expf(-zw1));
        float s1 = 1.0f / (1.0f + expf(-zs1));

        float4 v;
        v.x = fmaf(-w0, s0, 1.0f);        // a0
        v.y = w0 * (2.0f * s0 - 1.0f);    // b0
        v.z = fmaf(-w1, s1, 1.0f);        // a1
        v.w = w1 * (2.0f * s1 - 1.0f);    // b1
        abT[(size_t)o * 256 + p] = v;     // scattered 16B store (2MB total)
    } else {
        int t = (blk - 512) * 256 + threadIdx.x;  // 0..262143
        int q = t & 127;                          // lane-fast -> coalesced read
        int b = t >> 7;
        float4 v = ((const float4*)x)[(size_t)b * 128 + q];
        xt[((size_t)(b >> 4) * 128 + q) * R_ROWS + (b & 15)] = v;
    }
}

// ---------------------------------------------------------------------------
// Main. Block (256,4): lanes = o, y = i-chunk. Grid (2,128) = 256 blocks ->
// 1 block/CU, 16 waves/CU (4/SIMD).
// KEY (R6/R5 post-mortems): the x broadcast stream must stay OFF the scalar
// pipe — SMEM is out-of-order so every use forces lgkmcnt(0), draining even
// fresh prefetches, and the 102-SGPR file can't batch past L2 latency. A
// "divergent zero" (ds_swizzle identity minus tid — provably 0, opaque to
// uniformity analysis) keeps x on vector global_load: vmcnt is in-order,
// precisely waitable, with deep MSHRs; the TA merges the 64 identical lane
// addresses into one broadcast request. All hot-loop ab offsets are
// immediates off a fixed per-column base; x uses a single pointer bump per
// stage. No 64-bit math in the loop (R6's 3.3x VALU bloat).
// ---------------------------------------------------------------------------
__global__ __launch_bounds__(1024, 4) void fuzzy_main(
    const float4* __restrict__ abT,
    const float4* __restrict__ xt,
    float* __restrict__ out)
{
    __shared__ float part[W_CHUNK][R_ROWS][256];   // 64 KB (1 block/CU)

    const int o_l = threadIdx.x;              // 0..255
    const int o   = blockIdx.x * 256 + o_l;
    const int y   = __builtin_amdgcn_readfirstlane((int)threadIdx.y); // 0..3
    const int g   = blockIdx.y;               // b-group (16 rows)
    const int b0  = g * R_ROWS;

    // Divergent zero: swizzle 0x001F is the identity within each 32-lane
    // group, so dz == 0 on every lane, but divergence analysis must treat a
    // DS result as divergent -> derived x addresses stay on the vector path.
    int dz = __builtin_amdgcn_ds_swizzle((int)threadIdx.x, 0x001F)
           - (int)threadIdx.x;

    // ab column base for this (o, y): stage st uses float4s [2st, 2st+1],
    // byte offsets 32*st (+16) <= 1008 — all immediates.
    const float4* __restrict__ abp = abT + (size_t)o * 256 + (size_t)y * (2 * STAGES);
    // x slab pointer for this (g, y): advanced by 16 float4 (256B) per stage.
    const float4* __restrict__ xs =
        xt + ((size_t)g * 128 + (size_t)y * STAGES) * R_ROWS + dz;

    float acc[R_ROWS];
#pragma unroll
    for (int r = 0; r < R_ROWS; ++r) acc[r] = 1.0f;

    // ab ping registers, prefetched one stage ahead (~1 stage = ~370cyc >= L2).
    float4 pa = abp[0];
    float4 pb = abp[1];

    for (int st = 0; st < STAGES; ++st) {
        float4 c0 = pa, c1 = pb;              // (a0,b0,a1,b1) for i0,i1 / i2,i3
        int nst = (st + 1) & (STAGES - 1);    // wrap: last-iter prefetch dead but in-bounds
        pa = abp[2 * nst];
        pb = abp[2 * nst + 1];

#pragma unroll
        for (int r = 0; r < R_ROWS; ++r) {
            float4 xv = xs[r];                // broadcast vector load (vmcnt)
            float f0 = fmaf(c0.y, xv.x, c0.x);
            float f1 = fmaf(c0.w, xv.y, c0.z);
            float f2 = fmaf(c1.y, xv.z, c1.x);
            float f3 = fmaf(c1.w, xv.w, c1.z);
            acc[r] *= (f0 * f1) * (f2 * f3);
        }
        xs += R_ROWS;                         // +256B, simple pointer bump
    }

    // Combine 4 i-chunk partials per (row, o) via LDS, stride-1 conflict-free.
#pragma unroll
    for (int r = 0; r < R_ROWS; ++r)
        part[y][r][o_l] = acc[r];
    __syncthreads();
#pragma unroll
    for (int rr = 0; rr < R_ROWS / W_CHUNK; ++rr) {  // 4 rows per y-group
        int r = y * (R_ROWS / W_CHUNK) + rr;
        float v = part[0][r][o_l] * part[1][r][o_l]
                * part[2][r][o_l] * part[3][r][o_l];
        out[(size_t)(b0 + r) * O_DIM + o] = v;
    }
}

extern "C" void kernel_launch(void* const* d_in, const int* in_sizes, int n_in,
                              void* d_out, int out_size, void* d_ws, size_t ws_size,
                              hipStream_t stream) {
    const float* x        = (const float*)d_in[0];   // (B, I) fp32
    const float* w_logits = (const float*)d_in[1];   // (I, O) fp32
    const float* s_logits = (const float*)d_in[2];   // (I, O) fp32
    float* out = (float*)d_out;                      // (B, O) fp32
    float4* abT = (float4*)((char*)d_ws + ABT_OFFSET);   // [0, 2MB)
    float4* xt  = (float4*)((char*)d_ws + XT_OFFSET);    // [2MB, 6MB)

    // Fused setup: 512 abT-blocks + 1024 x-retile blocks.
    setup_kernel<<<dim3(1536), dim3(256), 0, stream>>>(
        x, w_logits, s_logits, abT, xt);

    // Grid (O/256, B/16) = (2, 128) = 256 blocks of (256,4)=1024 threads.
    fuzzy_main<<<dim3(O_DIM / 256, B_DIM / R_ROWS), dim3(256, W_CHUNK), 0, stream>>>(
        abT, xt, out);
}